// Round 2
// baseline (163.474 us; speedup 1.0000x reference)
//
#include <hip/hip_runtime.h>

#define Bsz 64
#define Ssz 512
#define Hsz 768
#define Tsz 9
#define LOG2E 1.4426950408889634f
#define LN2F  0.6931471805599453f

__device__ __forceinline__ float lane_bcast(float v, int l) {
    return __uint_as_float((unsigned)__builtin_amdgcn_readlane((int)__float_as_uint(v), l));
}

// ---------------- K1: emissions = enc @ fc_w^T + fc_b (natural units) ----------------
// grid = B*S/16 blocks of 256. 16 lanes per position, LDS-transpose reduce (no shuffles).
__global__ __launch_bounds__(256) void emis_kernel(
    const float* __restrict__ x, const float* __restrict__ fcw,
    const float* __restrict__ fcb, float* __restrict__ em) {
    __shared__ float4 w4[Tsz * Hsz / 4];          // 1728 float4 = 27.6 KB
    __shared__ float bias[Tsz];
    __shared__ float part[16 * Tsz * 16];         // [p][t][l] 9.2 KB
    const int tid = threadIdx.x;
    const float4* fw4 = reinterpret_cast<const float4*>(fcw);
#pragma unroll
    for (int i = 0; i < 7; ++i) {
        const int o = tid + i * 256;
        if (o < 1728) w4[o] = fw4[o];
    }
    if (tid < Tsz) bias[tid] = fcb[tid];
    __syncthreads();

    const int p = tid >> 4, l = tid & 15;
    const float4* xr = reinterpret_cast<const float4*>(
        x + ((size_t)blockIdx.x * 16 + p) * Hsz);
    float acc[Tsz];
#pragma unroll
    for (int t = 0; t < Tsz; ++t) acc[t] = 0.0f;
#pragma unroll
    for (int i = 0; i < 12; ++i) {
        const float4 xv = xr[i * 16 + l];
#pragma unroll
        for (int t = 0; t < Tsz; ++t) {
            const float4 wv = w4[t * 192 + i * 16 + l];
            acc[t] = fmaf(xv.x, wv.x, fmaf(xv.y, wv.y,
                     fmaf(xv.z, wv.z, fmaf(xv.w, wv.w, acc[t]))));
        }
    }
#pragma unroll
    for (int t = 0; t < Tsz; ++t) part[(p * Tsz + t) * 16 + l] = acc[t];
    __syncthreads();
    if (tid < 16 * Tsz) {
        const int t = tid % Tsz;
        float s = bias[t];
#pragma unroll
        for (int l2 = 0; l2 < 16; ++l2) s += part[tid * 16 + l2];
        em[(size_t)blockIdx.x * (16 * Tsz) + tid] = s;
    }
}

// ---------------- K2: chunked LSE forward pass 1 (probability domain) ----------------
// lane = (b, c, a): row a of chunk c's transfer matrix. 9216 lanes = 36 blocks x 256.
__global__ __launch_bounds__(256, 1) void lse1_kernel(
    const float* __restrict__ em, const int* __restrict__ mask,
    const float* __restrict__ trans, float* __restrict__ R2) {
    const int flat = blockIdx.x * 256 + threadIdx.x;   // < 9216 exactly
    const int a = flat % Tsz;
    const int bc = flat / Tsz;       // b*16 + c
    const int c = bc & 15;
    const int b = bc >> 4;

    float E[81];
#pragma unroll
    for (int i = 0; i < 81; ++i) E[i] = exp2f(trans[i] * LOG2E);

    float pp[Tsz];
#pragma unroll
    for (int j = 0; j < Tsz; ++j) pp[j] = (j == a) ? 1.0f : 0.0f;
    float K = 0.0f;

    const float* emb = em + (size_t)b * Ssz * Tsz;
    const int* mkb = mask + b * Ssz;
    const int s_lo = c * 32 + 1;
    const int s_hi = min(c * 32 + 32, Ssz - 1);

    float ec[Tsz];
#pragma unroll
    for (int j = 0; j < Tsz; ++j) ec[j] = emb[s_lo * Tsz + j];
    int mc = mkb[s_lo];

    for (int s = s_lo; s <= s_hi; ++s) {
        const int sp = (s < s_hi) ? s + 1 : s;
        float en[Tsz];
#pragma unroll
        for (int j = 0; j < Tsz; ++j) en[j] = emb[sp * Tsz + j];
        const int mn = mkb[sp];

        float g[Tsz];
#pragma unroll
        for (int j = 0; j < Tsz; ++j) g[j] = pp[0] * E[j];
#pragma unroll
        for (int i = 1; i < Tsz; ++i)
#pragma unroll
            for (int j = 0; j < Tsz; ++j) g[j] = fmaf(pp[i], E[i * Tsz + j], g[j]);
#pragma unroll
        for (int j = 0; j < Tsz; ++j) {
            const float ex = exp2f(ec[j] * LOG2E);
            const float np = g[j] * ex;
            if (mc > 0) pp[j] = np;
        }
        if (((s - s_lo) & 7) == 7) {
            float ss = 0.0f;
#pragma unroll
            for (int j = 0; j < Tsz; ++j) ss += pp[j];
            K += __log2f(ss);
            const float inv = 1.0f / ss;
#pragma unroll
            for (int j = 0; j < Tsz; ++j) pp[j] *= inv;
        }
#pragma unroll
        for (int j = 0; j < Tsz; ++j) ec[j] = en[j];
        mc = mn;
    }
    float* outp = R2 + ((size_t)bc * Tsz + a) * Tsz;
#pragma unroll
    for (int j = 0; j < Tsz; ++j) outp[j] = K + __log2f(pp[j]);
}

// ---------------- K3: exact Viterbi scan + backtrace, 1 block per batch ----------------
__device__ __forceinline__ void vstep(float& alpha, const float (&tc)[Tsz], float e,
                                      int mk, int j, unsigned char* bp, int s) {
    float v[Tsz];
#pragma unroll
    for (int i = 0; i < Tsz; ++i) v[i] = lane_bcast(alpha, i) + tc[i];
    // tournament argmax, FIRST max on ties (right wins only if strictly greater)
    float w01v = (v[1] > v[0]) ? v[1] : v[0]; int w01i = (v[1] > v[0]) ? 1 : 0;
    float w23v = (v[3] > v[2]) ? v[3] : v[2]; int w23i = (v[3] > v[2]) ? 3 : 2;
    float w45v = (v[5] > v[4]) ? v[5] : v[4]; int w45i = (v[5] > v[4]) ? 5 : 4;
    float w67v = (v[7] > v[6]) ? v[7] : v[6]; int w67i = (v[7] > v[6]) ? 7 : 6;
    float x03v = (w23v > w01v) ? w23v : w01v; int x03i = (w23v > w01v) ? w23i : w01i;
    float x47v = (w67v > w45v) ? w67v : w45v; int x47i = (w67v > w45v) ? w67i : w45i;
    float y07v = (x47v > x03v) ? x47v : x03v; int y07i = (x47v > x03v) ? x47i : x03i;
    const float bv = (v[8] > y07v) ? v[8] : y07v;
    const int   bi = (v[8] > y07v) ? 8 : y07i;
    bp[(s - 1) * Tsz + j] = (unsigned char)((mk > 0) ? bi : j);
    alpha = (mk > 0) ? (bv + e) : alpha;
}

__global__ __launch_bounds__(64) void vit_kernel(
    const float* __restrict__ em, const int* __restrict__ mask,
    const float* __restrict__ start_t, const float* __restrict__ end_t,
    const float* __restrict__ trans, float* __restrict__ out_path) {
    __shared__ unsigned char bp[(Ssz - 1) * Tsz];   // 4599 B
    __shared__ unsigned char mapA[64][12];
    __shared__ unsigned char mapB[64][12];
    const int b = blockIdx.x, lane = threadIdx.x;
    const float* emb = em + (size_t)b * Ssz * Tsz;
    const int* mkb = mask + b * Ssz;
    const int j = (lane < Tsz) ? lane : Tsz - 1;

    float tc[Tsz];
#pragma unroll
    for (int i = 0; i < Tsz; ++i) tc[i] = trans[i * Tsz + j];
    float alpha = start_t[j] + emb[j];

    if (lane < Tsz) {
        // 8-deep register prefetch ring (compile-time slots via x8 unroll)
        float er[8];
        int mr[8];
#pragma unroll
        for (int k = 0; k < 8; ++k) {
            er[k] = emb[(1 + k) * Tsz + j];
            mr[k] = mkb[1 + k];
        }
        for (int sb = 1; sb <= 497; sb += 8) {
#pragma unroll
            for (int k = 0; k < 8; ++k) {
                const int s = sb + k;
                const float ecur = er[k];
                const int mcur = mr[k];
                int s8 = s + 8;
                if (s8 > Ssz - 1) s8 = Ssz - 1;
                er[k] = emb[s8 * Tsz + j];
                mr[k] = mkb[s8];
                vstep(alpha, tc, ecur, mcur, j, bp, s);
            }
        }
#pragma unroll
        for (int k = 0; k < 7; ++k) vstep(alpha, tc, er[k], mr[k], j, bp, 505 + k);
    }

    // final argmax over states (first max on ties)
    float v = (lane < Tsz) ? alpha + end_t[j] : -3.0e38f;
    int idx = lane;
#pragma unroll
    for (int off = 32; off >= 1; off >>= 1) {
        const float ov = __shfl_xor(v, off, 64);
        const int oi = __shfl_xor(idx, off, 64);
        if (ov > v || (ov == v && oi < idx)) { v = ov; idx = oi; }
    }
    const int last = idx;
    __syncthreads();

    // per-chunk composed map f_l = bp[lo] ∘ ... ∘ bp[hi]
    const int lo = lane * 8;
    const int hi = min(lo + 7, Ssz - 2);
    int xf[Tsz];
#pragma unroll
    for (int t = 0; t < Tsz; ++t) xf[t] = t;
    for (int k = hi; k >= lo; --k) {
#pragma unroll
        for (int t = 0; t < Tsz; ++t) xf[t] = bp[k * Tsz + xf[t]];
    }
#pragma unroll
    for (int t = 0; t < Tsz; ++t) mapA[lane][t] = (unsigned char)xf[t];
    __syncthreads();

    // suffix-composition doubling: S_l = f_l ∘ f_{l+1} ∘ ... ∘ f_63
#define VIT_RND(CUR, NXT, D)                                              \
    {                                                                     \
        const int o = lane + (D);                                         \
        unsigned char nn[Tsz];                                            \
        if (o < 64) {                                                     \
            _Pragma("unroll") for (int t = 0; t < Tsz; ++t)               \
                nn[t] = CUR[lane][CUR[o][t]];                             \
        } else {                                                          \
            _Pragma("unroll") for (int t = 0; t < Tsz; ++t)               \
                nn[t] = CUR[lane][t];                                     \
        }                                                                 \
        __syncthreads();                                                  \
        _Pragma("unroll") for (int t = 0; t < Tsz; ++t) NXT[lane][t] = nn[t]; \
        __syncthreads();                                                  \
    }
    VIT_RND(mapA, mapB, 1)
    VIT_RND(mapB, mapA, 2)
    VIT_RND(mapA, mapB, 4)
    VIT_RND(mapB, mapA, 8)
    VIT_RND(mapA, mapB, 16)
    VIT_RND(mapB, mapA, 32)
#undef VIT_RND

    // entry tag for this chunk = S_{l+1}(last) = tag at position hi+1
    int t = (lane == 63) ? last : (int)mapA[lane + 1][last];
    float* op = out_path + (size_t)b * Ssz;
    for (int k = hi; k >= lo; --k) {
        t = bp[k * Tsz + t];
        op[k] = (float)t;
    }
    if (lane == 0) op[Ssz - 1] = (float)last;
}

// ---------------- K4: denominator combine + numerator + loss + lengths ----------------
// 1 block x 1024: 16 lanes per batch element.
__global__ __launch_bounds__(1024) void fin_kernel(
    const float* __restrict__ em, const int* __restrict__ labels,
    const int* __restrict__ mask, const int* __restrict__ lengths,
    const float* __restrict__ start_t, const float* __restrict__ end_t,
    const float* __restrict__ trans, const float* __restrict__ R2,
    float* __restrict__ dout) {
    __shared__ float sh_tr[81];
    __shared__ float llb[Bsz];
    const int tid = threadIdx.x;
    if (tid < 81) sh_tr[tid] = trans[tid];
    __syncthreads();

    const int b = tid >> 4, jj = tid & 15, j = (jj < Tsz) ? jj : Tsz - 1;
    const float* emb = em + (size_t)b * Ssz * Tsz;
    const int* mkb = mask + b * Ssz;
    const int* lbb = labels + b * Ssz;
    const int gb = (tid & 63) & ~15;   // group base lane within wave

    // denominator: alpha2 in log2 domain, combine 16 chunk transfer matrices
    float alpha2 = (start_t[j] + emb[j]) * LOG2E;
    const float* r2b = R2 + (size_t)b * 16 * 81;

#define COMBINE(RC)                                                        \
    {                                                                      \
        float xi[Tsz];                                                     \
        _Pragma("unroll") for (int i = 0; i < Tsz; ++i)                    \
            xi[i] = __shfl(alpha2, gb + i, 64) + (RC)[i];                  \
        float m = xi[0];                                                   \
        _Pragma("unroll") for (int i = 1; i < Tsz; ++i) m = fmaxf(m, xi[i]); \
        float sm = 0.0f;                                                   \
        _Pragma("unroll") for (int i = 0; i < Tsz; ++i)                    \
            sm += exp2f(xi[i] - m);                                        \
        alpha2 = m + __log2f(sm);                                          \
    }

    float rcA[Tsz], rcB[Tsz];
#pragma unroll
    for (int i = 0; i < Tsz; ++i) rcA[i] = r2b[i * Tsz + j];
    for (int c2 = 0; c2 < 16; c2 += 2) {
#pragma unroll
        for (int i = 0; i < Tsz; ++i) rcB[i] = r2b[((c2 + 1) * Tsz + i) * Tsz + j];
        COMBINE(rcA)
        if (c2 + 2 < 16) {
#pragma unroll
            for (int i = 0; i < Tsz; ++i) rcA[i] = r2b[((c2 + 2) * Tsz + i) * Tsz + j];
        }
        COMBINE(rcB)
    }
#undef COMBINE

    float dv = (jj < Tsz) ? alpha2 + end_t[j] * LOG2E : -3.0e38f;
    float dm = dv;
#pragma unroll
    for (int off = 8; off >= 1; off >>= 1) dm = fmaxf(dm, __shfl_xor(dm, off, 64));
    float dsum = (jj < Tsz) ? exp2f(dv - dm) : 0.0f;
#pragma unroll
    for (int off = 8; off >= 1; off >>= 1) dsum += __shfl_xor(dsum, off, 64);
    const float den2 = dm + __log2f(dsum);

    // numerator (natural units, exact formula as reference)
    float part = 0.0f;
#pragma unroll 4
    for (int s = 1 + jj; s < Ssz; s += 16) {
        if (mkb[s] > 0) {
            const int tg = lbb[s];
            int pq = s - 1;
            while (pq > 0 && mkb[pq] == 0) --pq;
            part += sh_tr[lbb[pq] * Tsz + tg] + emb[s * Tsz + tg];
        }
    }
#pragma unroll
    for (int off = 8; off >= 1; off >>= 1) part += __shfl_xor(part, off, 64);
    if (jj == 0) {
        const int tg0 = lbb[0];
        float num = part + start_t[tg0] + emb[tg0];
        int pq = Ssz - 1;
        while (pq > 0 && mkb[pq] == 0) --pq;
        num += end_t[lbb[pq]];
        llb[b] = num - den2 * LN2F;
    }
    __syncthreads();
    if (tid < Bsz) {
        float s = llb[tid];
#pragma unroll
        for (int off = 32; off >= 1; off >>= 1) s += __shfl_xor(s, off, 64);
        if (tid == 0) dout[0] = -s * (1.0f / (float)Bsz);
        dout[1 + Bsz * Ssz + tid] = (float)lengths[tid];
    }
}

extern "C" void kernel_launch(void* const* d_in, const int* in_sizes, int n_in,
                              void* d_out, int out_size, void* d_ws, size_t ws_size,
                              hipStream_t stream) {
    const float* enc    = (const float*)d_in[0];
    const int*   labels = (const int*)d_in[1];
    const int*   mask   = (const int*)d_in[2];
    const int*   lengths= (const int*)d_in[3];
    const float* fcw    = (const float*)d_in[4];
    const float* fcb    = (const float*)d_in[5];
    const float* startt = (const float*)d_in[6];
    const float* endt   = (const float*)d_in[7];
    const float* trans  = (const float*)d_in[8];

    float* out = (float*)d_out;
    float* em  = (float*)d_ws;                              // B*S*T floats
    float* R2  = em + (size_t)Bsz * Ssz * Tsz;              // B*16*9*9 floats

    emis_kernel<<<Bsz * Ssz / 16, 256, 0, stream>>>(enc, fcw, fcb, em);
    lse1_kernel<<<36, 256, 0, stream>>>(em, mask, trans, R2);
    vit_kernel<<<Bsz, 64, 0, stream>>>(em, mask, startt, endt, trans, out + 1);
    fin_kernel<<<1, 1024, 0, stream>>>(em, labels, mask, lengths, startt, endt,
                                       trans, R2, out);
}

// Round 3
// 106.381 us; speedup vs baseline: 1.5367x; 1.5367x over previous
//
#include <hip/hip_runtime.h>

#define Bsz 64
#define Ssz 512
#define Hsz 768
#define Tsz 9
#define NCH 16
#define LOG2E 1.4426950408889634f
#define LN2F  0.6931471805599453f

// ---------------- K1: emissions = enc @ fc_w^T + fc_b ----------------
__global__ __launch_bounds__(256) void emis_kernel(
    const float* __restrict__ x, const float* __restrict__ fcw,
    const float* __restrict__ fcb, float* __restrict__ em) {
    __shared__ float4 w4[Tsz * Hsz / 4];
    __shared__ float bias[Tsz];
    __shared__ float part[16 * Tsz * 16];
    const int tid = threadIdx.x;
    const float4* fw4 = reinterpret_cast<const float4*>(fcw);
#pragma unroll
    for (int i = 0; i < 7; ++i) {
        const int o = tid + i * 256;
        if (o < 1728) w4[o] = fw4[o];
    }
    if (tid < Tsz) bias[tid] = fcb[tid];
    __syncthreads();

    const int p = tid >> 4, l = tid & 15;
    const float4* xr = reinterpret_cast<const float4*>(
        x + ((size_t)blockIdx.x * 16 + p) * Hsz);
    float acc[Tsz];
#pragma unroll
    for (int t = 0; t < Tsz; ++t) acc[t] = 0.0f;
#pragma unroll
    for (int i = 0; i < 12; ++i) {
        const float4 xv = xr[i * 16 + l];
#pragma unroll
        for (int t = 0; t < Tsz; ++t) {
            const float4 wv = w4[t * 192 + i * 16 + l];
            acc[t] = fmaf(xv.x, wv.x, fmaf(xv.y, wv.y,
                     fmaf(xv.z, wv.z, fmaf(xv.w, wv.w, acc[t]))));
        }
    }
#pragma unroll
    for (int t = 0; t < Tsz; ++t) part[(p * Tsz + t) * 16 + l] = acc[t];
    __syncthreads();
    if (tid < 16 * Tsz) {
        const int t = tid % Tsz;
        float s = bias[t];
#pragma unroll
        for (int l2 = 0; l2 < 16; ++l2) s += part[tid * 16 + l2];
        em[(size_t)blockIdx.x * (16 * Tsz) + tid] = s;
    }
}

// ---------------- K2: chunk transfer matrices (LSE prob-domain + Viterbi max-plus) ----
// blocks 0..35: LSE rows (9216 lanes). blocks 36..71: Viterbi rows (9216 lanes).
__global__ __launch_bounds__(256, 1) void pass1_kernel(
    const float* __restrict__ em, const int* __restrict__ mask,
    const float* __restrict__ trans, float* __restrict__ R2,
    float* __restrict__ MV) {
    const int tid = threadIdx.x;
    if (blockIdx.x < 36) {
        const int flat = blockIdx.x * 256 + tid;
        const int a = flat % Tsz;
        const int bc = flat / Tsz;
        const int c = bc & 15;
        const int b = bc >> 4;

        float E[81];
#pragma unroll
        for (int i = 0; i < 81; ++i) E[i] = exp2f(trans[i] * LOG2E);

        float pp[Tsz];
#pragma unroll
        for (int j = 0; j < Tsz; ++j) pp[j] = (j == a) ? 1.0f : 0.0f;
        float K = 0.0f;

        const float* emb = em + (size_t)b * Ssz * Tsz;
        const int* mkb = mask + b * Ssz;
        const int s_lo = c * 32 + 1;
        const int s_hi = min(c * 32 + 32, Ssz - 1);

        float ec[Tsz];
#pragma unroll
        for (int j = 0; j < Tsz; ++j) ec[j] = emb[s_lo * Tsz + j];
        int mc = mkb[s_lo];

        for (int s = s_lo; s <= s_hi; ++s) {
            const int sp = (s < s_hi) ? s + 1 : s;
            float en[Tsz];
#pragma unroll
            for (int j = 0; j < Tsz; ++j) en[j] = emb[sp * Tsz + j];
            const int mn = mkb[sp];

            float g[Tsz];
#pragma unroll
            for (int j = 0; j < Tsz; ++j) g[j] = pp[0] * E[j];
#pragma unroll
            for (int i = 1; i < Tsz; ++i)
#pragma unroll
                for (int j = 0; j < Tsz; ++j) g[j] = fmaf(pp[i], E[i * Tsz + j], g[j]);
#pragma unroll
            for (int j = 0; j < Tsz; ++j) {
                const float ex = exp2f(ec[j] * LOG2E);
                const float np = g[j] * ex;
                if (mc > 0) pp[j] = np;
            }
            if (((s - s_lo) & 7) == 7) {
                float ss = 0.0f;
#pragma unroll
                for (int j = 0; j < Tsz; ++j) ss += pp[j];
                K += __log2f(ss);
                const float inv = 1.0f / ss;
#pragma unroll
                for (int j = 0; j < Tsz; ++j) pp[j] *= inv;
            }
#pragma unroll
            for (int j = 0; j < Tsz; ++j) ec[j] = en[j];
            mc = mn;
        }
        float* outp = R2 + ((size_t)bc * Tsz + a) * Tsz;
#pragma unroll
        for (int j = 0; j < Tsz; ++j) outp[j] = K + __log2f(pp[j]);
    } else {
        // ---- Viterbi max-plus chunk transfer rows ----
        const int flat = (blockIdx.x - 36) * 256 + tid;
        const int a = flat % Tsz;
        const int bc = flat / Tsz;
        const int c = bc & 15;
        const int b = bc >> 4;

        float T[81];
#pragma unroll
        for (int i = 0; i < 81; ++i) T[i] = trans[i];

        float row[Tsz];
#pragma unroll
        for (int j = 0; j < Tsz; ++j) row[j] = (j == a) ? 0.0f : -1e30f;

        const float* emb = em + (size_t)b * Ssz * Tsz;
        const int* mkb = mask + b * Ssz;
        const int s_lo = c * 32 + 1;
        const int s_hi = min(c * 32 + 32, Ssz - 1);

        float ec[Tsz];
#pragma unroll
        for (int j = 0; j < Tsz; ++j) ec[j] = emb[s_lo * Tsz + j];
        int mc = mkb[s_lo];

        for (int s = s_lo; s <= s_hi; ++s) {
            const int sp = (s < s_hi) ? s + 1 : s;
            float en[Tsz];
#pragma unroll
            for (int j = 0; j < Tsz; ++j) en[j] = emb[sp * Tsz + j];
            const int mn = mkb[sp];

            float g[Tsz];
#pragma unroll
            for (int j = 0; j < Tsz; ++j) g[j] = row[0] + T[j];
#pragma unroll
            for (int i = 1; i < Tsz; ++i)
#pragma unroll
                for (int j = 0; j < Tsz; ++j) g[j] = fmaxf(g[j], row[i] + T[i * Tsz + j]);
#pragma unroll
            for (int j = 0; j < Tsz; ++j)
                if (mc > 0) row[j] = g[j] + ec[j];
#pragma unroll
            for (int j = 0; j < Tsz; ++j) ec[j] = en[j];
            mc = mn;
        }
        float* o = MV + (size_t)bc * 81 + a * Tsz;
#pragma unroll
        for (int j = 0; j < Tsz; ++j) o[j] = row[j];
    }
}

// first-max argmax of 9 values (strict > keeps FIRST max)
__device__ __forceinline__ void amax9(const float (&v)[Tsz], float& bv, int& bi) {
    float w01v = (v[1] > v[0]) ? v[1] : v[0]; int w01i = (v[1] > v[0]) ? 1 : 0;
    float w23v = (v[3] > v[2]) ? v[3] : v[2]; int w23i = (v[3] > v[2]) ? 3 : 2;
    float w45v = (v[5] > v[4]) ? v[5] : v[4]; int w45i = (v[5] > v[4]) ? 5 : 4;
    float w67v = (v[7] > v[6]) ? v[7] : v[6]; int w67i = (v[7] > v[6]) ? 7 : 6;
    float x03v = (w23v > w01v) ? w23v : w01v; int x03i = (w23v > w01v) ? w23i : w01i;
    float x47v = (w67v > w45v) ? w67v : w45v; int x47i = (w67v > w45v) ? w67i : w45i;
    float y07v = (x47v > x03v) ? x47v : x03v; int y07i = (x47v > x03v) ? x47i : x03i;
    bv = (v[8] > y07v) ? v[8] : y07v;
    bi = (v[8] > y07v) ? 8 : y07i;
}

// ---------------- K3: per-batch finish: vit pass2+3, backtrace, den combine, num ----
__global__ __launch_bounds__(64) void vit2_kernel(
    const float* __restrict__ em, const int* __restrict__ labels,
    const int* __restrict__ mask, const float* __restrict__ start_t,
    const float* __restrict__ end_t, const float* __restrict__ trans,
    const float* __restrict__ R2, const float* __restrict__ MV,
    float* __restrict__ out_path, float* __restrict__ ll) {
    __shared__ __align__(16) float em_s[Ssz * Tsz];
    __shared__ __align__(16) int mk_s[Ssz];
    __shared__ __align__(16) float mv_s[NCH * 81];
    __shared__ float tr_s[81];
    __shared__ float st_s[Tsz], en_s[Tsz];
    __shared__ unsigned char bp[(Ssz - 1) * Tsz];
    __shared__ unsigned char mapA[64][12], mapB[64][12];
    __shared__ float afin[Tsz];
    __shared__ float den_sh;

    const int b = blockIdx.x, lane = threadIdx.x;
    const float* emb = em + (size_t)b * Ssz * Tsz;
    const int* mkb = mask + b * Ssz;
    const int* lbb = labels + b * Ssz;

    // ---- cooperative LDS staging ----
    {
        const float4* s4 = reinterpret_cast<const float4*>(emb);
        float4* d4 = reinterpret_cast<float4*>(em_s);
        for (int i = lane; i < Ssz * Tsz / 4; i += 64) d4[i] = s4[i];
        const int4* m4 = reinterpret_cast<const int4*>(mkb);
        int4* md = reinterpret_cast<int4*>(mk_s);
        for (int i = lane; i < Ssz / 4; i += 64) md[i] = m4[i];
        const float4* v4 = reinterpret_cast<const float4*>(MV + (size_t)b * NCH * 81);
        float4* vd = reinterpret_cast<float4*>(mv_s);
        for (int i = lane; i < NCH * 81 / 4; i += 64) vd[i] = v4[i];
        for (int i = lane; i < 81; i += 64) tr_s[i] = trans[i];
        if (lane < Tsz) { st_s[lane] = start_t[lane]; en_s[lane] = end_t[lane]; }
    }
    __syncthreads();

    // ---- pass2 (prefix combine) + pass3 (chunk scan with bp) on threads 0..15 ----
    if (lane < NCH) {
        const int c = lane;
        float al[Tsz];
#pragma unroll
        for (int j = 0; j < Tsz; ++j) al[j] = st_s[j] + em_s[j];
        for (int cc = 0; cc < c; ++cc) {
            const float* M = &mv_s[cc * 81];
            float g[Tsz];
#pragma unroll
            for (int j = 0; j < Tsz; ++j) {
                float m = al[0] + M[j];
#pragma unroll
                for (int i = 1; i < Tsz; ++i) m = fmaxf(m, al[i] + M[i * Tsz + j]);
                g[j] = m;
            }
#pragma unroll
            for (int j = 0; j < Tsz; ++j) al[j] = g[j];
        }

        float TR[81];
#pragma unroll
        for (int i = 0; i < 81; ++i) TR[i] = tr_s[i];

        const int s_lo = c * 32 + 1;
        const int s_hi = min(c * 32 + 32, Ssz - 1);
        for (int s = s_lo; s <= s_hi; ++s) {
            const int mk = mk_s[s];
            float g[Tsz];
            int bi9[Tsz];
#pragma unroll
            for (int j = 0; j < Tsz; ++j) {
                float v[Tsz];
#pragma unroll
                for (int i = 0; i < Tsz; ++i) v[i] = al[i] + TR[i * Tsz + j];
                float bv; int bi;
                amax9(v, bv, bi);
                g[j] = bv; bi9[j] = bi;
            }
#pragma unroll
            for (int j = 0; j < Tsz; ++j) {
                bp[(s - 1) * Tsz + j] = (unsigned char)((mk > 0) ? bi9[j] : j);
                al[j] = (mk > 0) ? g[j] + em_s[s * Tsz + j] : al[j];
            }
        }
        if (c == NCH - 1) {
#pragma unroll
            for (int j = 0; j < Tsz; ++j) afin[j] = al[j];
        }
    }
    __syncthreads();

    // ---- final tag (all lanes redundantly) ----
    float bb = afin[0] + en_s[0];
    int last = 0;
#pragma unroll
    for (int q = 1; q < Tsz; ++q) {
        const float qq = afin[q] + en_s[q];
        if (qq > bb) { bb = qq; last = q; }
    }

    // ---- backtrace: per-lane 8-step composed maps + suffix doubling ----
    const int lo = lane * 8;
    const int hi = min(lo + 7, Ssz - 2);
    int xf[Tsz];
#pragma unroll
    for (int t = 0; t < Tsz; ++t) xf[t] = t;
    for (int k = hi; k >= lo; --k) {
#pragma unroll
        for (int t = 0; t < Tsz; ++t) xf[t] = bp[k * Tsz + xf[t]];
    }
#pragma unroll
    for (int t = 0; t < Tsz; ++t) mapA[lane][t] = (unsigned char)xf[t];
    __syncthreads();

#define VIT_RND(CUR, NXT, D)                                              \
    {                                                                     \
        const int o = lane + (D);                                         \
        unsigned char nn[Tsz];                                            \
        if (o < 64) {                                                     \
            _Pragma("unroll") for (int t = 0; t < Tsz; ++t)               \
                nn[t] = CUR[lane][CUR[o][t]];                             \
        } else {                                                          \
            _Pragma("unroll") for (int t = 0; t < Tsz; ++t)               \
                nn[t] = CUR[lane][t];                                     \
        }                                                                 \
        __syncthreads();                                                  \
        _Pragma("unroll") for (int t = 0; t < Tsz; ++t) NXT[lane][t] = nn[t]; \
        __syncthreads();                                                  \
    }
    VIT_RND(mapA, mapB, 1)
    VIT_RND(mapB, mapA, 2)
    VIT_RND(mapA, mapB, 4)
    VIT_RND(mapB, mapA, 8)
    VIT_RND(mapA, mapB, 16)
    VIT_RND(mapB, mapA, 32)
#undef VIT_RND

    {
        int t = (lane == 63) ? last : (int)mapA[lane + 1][last];
        float* op = out_path + (size_t)b * Ssz;
        for (int k = hi; k >= lo; --k) {
            t = bp[k * Tsz + t];
            op[k] = (float)t;
        }
        if (lane == 0) op[Ssz - 1] = (float)last;
    }

    // ---- denominator combine (lanes 0..15, 16-lane group reduce) ----
    if (lane < 16) {
        const int jj = lane, j = (jj < Tsz) ? jj : Tsz - 1;
        float alpha2 = (st_s[j] + em_s[j]) * LOG2E;
        const float* r2b = R2 + (size_t)b * NCH * 81;

#define COMBINE(RC)                                                        \
        {                                                                  \
            float xi[Tsz];                                                 \
            _Pragma("unroll") for (int i = 0; i < Tsz; ++i)                \
                xi[i] = __shfl(alpha2, i, 64) + (RC)[i];                   \
            float m = xi[0];                                               \
            _Pragma("unroll") for (int i = 1; i < Tsz; ++i) m = fmaxf(m, xi[i]); \
            float sm = 0.0f;                                               \
            _Pragma("unroll") for (int i = 0; i < Tsz; ++i)                \
                sm += exp2f(xi[i] - m);                                    \
            alpha2 = m + __log2f(sm);                                      \
        }

        float rcA[Tsz], rcB[Tsz];
#pragma unroll
        for (int i = 0; i < Tsz; ++i) rcA[i] = r2b[i * Tsz + j];
        for (int c2 = 0; c2 < NCH; c2 += 2) {
#pragma unroll
            for (int i = 0; i < Tsz; ++i) rcB[i] = r2b[((c2 + 1) * Tsz + i) * Tsz + j];
            COMBINE(rcA)
            if (c2 + 2 < NCH) {
#pragma unroll
                for (int i = 0; i < Tsz; ++i) rcA[i] = r2b[((c2 + 2) * Tsz + i) * Tsz + j];
            }
            COMBINE(rcB)
        }
#undef COMBINE

        float dv = (jj < Tsz) ? alpha2 + en_s[j] * LOG2E : -3.0e38f;
        float dm = dv;
#pragma unroll
        for (int off = 8; off >= 1; off >>= 1) dm = fmaxf(dm, __shfl_xor(dm, off, 64));
        float dsum = (jj < Tsz) ? exp2f(dv - dm) : 0.0f;
#pragma unroll
        for (int off = 8; off >= 1; off >>= 1) dsum += __shfl_xor(dsum, off, 64);
        if (jj == 0) den_sh = dm + __log2f(dsum);
    }
    __syncthreads();

    // ---- numerator (all 64 lanes) + ll ----
    float part = 0.0f;
    for (int s = 1 + lane; s < Ssz; s += 64) {
        if (mk_s[s] > 0) {
            const int tg = lbb[s];
            int pq = s - 1;
            while (pq > 0 && mk_s[pq] == 0) --pq;
            part += tr_s[lbb[pq] * Tsz + tg] + em_s[s * Tsz + tg];
        }
    }
#pragma unroll
    for (int off = 32; off >= 1; off >>= 1) part += __shfl_xor(part, off, 64);
    if (lane == 0) {
        const int tg0 = lbb[0];
        float num = part + st_s[tg0] + em_s[tg0];
        int pq = Ssz - 1;
        while (pq > 0 && mk_s[pq] == 0) --pq;
        num += en_s[lbb[pq]];
        ll[b] = num - den_sh * LN2F;
    }
}

// ---------------- K4: loss reduce + lengths ----------------
__global__ __launch_bounds__(64) void fin2_kernel(const float* __restrict__ ll,
                                                  const int* __restrict__ lengths,
                                                  float* __restrict__ dout) {
    const int lane = threadIdx.x;
    float v = ll[lane];
#pragma unroll
    for (int off = 32; off >= 1; off >>= 1) v += __shfl_xor(v, off, 64);
    if (lane == 0) dout[0] = -v * (1.0f / (float)Bsz);
    dout[1 + Bsz * Ssz + lane] = (float)lengths[lane];
}

extern "C" void kernel_launch(void* const* d_in, const int* in_sizes, int n_in,
                              void* d_out, int out_size, void* d_ws, size_t ws_size,
                              hipStream_t stream) {
    const float* enc    = (const float*)d_in[0];
    const int*   labels = (const int*)d_in[1];
    const int*   mask   = (const int*)d_in[2];
    const int*   lengths= (const int*)d_in[3];
    const float* fcw    = (const float*)d_in[4];
    const float* fcb    = (const float*)d_in[5];
    const float* startt = (const float*)d_in[6];
    const float* endt   = (const float*)d_in[7];
    const float* trans  = (const float*)d_in[8];

    float* out = (float*)d_out;
    float* em  = (float*)d_ws;                                // 294912 f
    float* R2  = em + (size_t)Bsz * Ssz * Tsz;                // 82944 f
    float* MV  = R2 + (size_t)Bsz * NCH * 81;                 // 82944 f
    float* ll  = MV + (size_t)Bsz * NCH * 81;                 // 64 f

    emis_kernel<<<Bsz * Ssz / 16, 256, 0, stream>>>(enc, fcw, fcb, em);
    pass1_kernel<<<72, 256, 0, stream>>>(em, mask, trans, R2, MV);
    vit2_kernel<<<Bsz, 64, 0, stream>>>(em, labels, mask, startt, endt, trans,
                                        R2, MV, out + 1, ll);
    fin2_kernel<<<1, 64, 0, stream>>>(ll, lengths, out);
}

// Round 4
// 65.349 us; speedup vs baseline: 2.5016x; 1.6279x over previous
//
#include <hip/hip_runtime.h>

#define Bsz 64
#define Ssz 512
#define Hsz 768
#define Tsz 9
#define NCH 16
#define LOG2E 1.4426950408889634f
#define LN2F  0.6931471805599453f

__device__ __forceinline__ int SK(int s) { return s * Tsz + ((s >> 5) << 1); }

// ---------------- K1: emissions = enc @ fc_w^T + fc_b ----------------
__global__ __launch_bounds__(256) void emis_kernel(
    const float* __restrict__ x, const float* __restrict__ fcw,
    const float* __restrict__ fcb, float* __restrict__ em) {
    __shared__ float4 w4[Tsz * Hsz / 4];
    __shared__ float bias[Tsz];
    __shared__ float part[16 * Tsz * 16];
    const int tid = threadIdx.x;
    const float4* fw4 = reinterpret_cast<const float4*>(fcw);
#pragma unroll
    for (int i = 0; i < 7; ++i) {
        const int o = tid + i * 256;
        if (o < 1728) w4[o] = fw4[o];
    }
    if (tid < Tsz) bias[tid] = fcb[tid];
    __syncthreads();

    const int p = tid >> 4, l = tid & 15;
    const float4* xr = reinterpret_cast<const float4*>(
        x + ((size_t)blockIdx.x * 16 + p) * Hsz);
    float acc[Tsz];
#pragma unroll
    for (int t = 0; t < Tsz; ++t) acc[t] = 0.0f;
#pragma unroll
    for (int i = 0; i < 12; ++i) {
        const float4 xv = xr[i * 16 + l];
#pragma unroll
        for (int t = 0; t < Tsz; ++t) {
            const float4 wv = w4[t * 192 + i * 16 + l];
            acc[t] = fmaf(xv.x, wv.x, fmaf(xv.y, wv.y,
                     fmaf(xv.z, wv.z, fmaf(xv.w, wv.w, acc[t]))));
        }
    }
#pragma unroll
    for (int t = 0; t < Tsz; ++t) part[(p * Tsz + t) * 16 + l] = acc[t];
    __syncthreads();
    if (tid < 16 * Tsz) {
        const int t = tid % Tsz;
        float s = bias[t];
#pragma unroll
        for (int l2 = 0; l2 < 16; ++l2) s += part[tid * 16 + l2];
        em[(size_t)blockIdx.x * (16 * Tsz) + tid] = s;
    }
}

// ---------------- K2: chunk transfer matrices (LSE + Viterbi max-plus) ----------
__global__ __launch_bounds__(256, 1) void pass1_kernel(
    const float* __restrict__ em, const int* __restrict__ mask,
    const float* __restrict__ trans, float* __restrict__ R2,
    float* __restrict__ MV) {
    const int tid = threadIdx.x;
    if (blockIdx.x < 36) {
        const int flat = blockIdx.x * 256 + tid;
        const int a = flat % Tsz;
        const int bc = flat / Tsz;
        const int c = bc & 15;
        const int b = bc >> 4;

        float E[81];
#pragma unroll
        for (int i = 0; i < 81; ++i) E[i] = exp2f(trans[i] * LOG2E);

        float pp[Tsz];
#pragma unroll
        for (int j = 0; j < Tsz; ++j) pp[j] = (j == a) ? 1.0f : 0.0f;
        float K = 0.0f;

        const float* emb = em + (size_t)b * Ssz * Tsz;
        const int* mkb = mask + b * Ssz;
        const int s_lo = c * 32 + 1;
        const int s_hi = min(c * 32 + 32, Ssz - 1);

        float ec[Tsz];
#pragma unroll
        for (int j = 0; j < Tsz; ++j) ec[j] = emb[s_lo * Tsz + j];
        int mc = mkb[s_lo];

        for (int s = s_lo; s <= s_hi; ++s) {
            const int sp = (s < s_hi) ? s + 1 : s;
            float en[Tsz];
#pragma unroll
            for (int j = 0; j < Tsz; ++j) en[j] = emb[sp * Tsz + j];
            const int mn = mkb[sp];

            float g[Tsz];
#pragma unroll
            for (int j = 0; j < Tsz; ++j) g[j] = pp[0] * E[j];
#pragma unroll
            for (int i = 1; i < Tsz; ++i)
#pragma unroll
                for (int j = 0; j < Tsz; ++j) g[j] = fmaf(pp[i], E[i * Tsz + j], g[j]);
#pragma unroll
            for (int j = 0; j < Tsz; ++j) {
                const float ex = exp2f(ec[j] * LOG2E);
                const float np = g[j] * ex;
                if (mc > 0) pp[j] = np;
            }
            if (((s - s_lo) & 7) == 7) {
                float ss = 0.0f;
#pragma unroll
                for (int j = 0; j < Tsz; ++j) ss += pp[j];
                K += __log2f(ss);
                const float inv = 1.0f / ss;
#pragma unroll
                for (int j = 0; j < Tsz; ++j) pp[j] *= inv;
            }
#pragma unroll
            for (int j = 0; j < Tsz; ++j) ec[j] = en[j];
            mc = mn;
        }
        float* outp = R2 + ((size_t)bc * Tsz + a) * Tsz;
#pragma unroll
        for (int j = 0; j < Tsz; ++j) outp[j] = K + __log2f(pp[j]);
    } else {
        const int flat = (blockIdx.x - 36) * 256 + tid;
        const int a = flat % Tsz;
        const int bc = flat / Tsz;
        const int c = bc & 15;
        const int b = bc >> 4;

        float T[81];
#pragma unroll
        for (int i = 0; i < 81; ++i) T[i] = trans[i];

        float row[Tsz];
#pragma unroll
        for (int j = 0; j < Tsz; ++j) row[j] = (j == a) ? 0.0f : -1e30f;

        const float* emb = em + (size_t)b * Ssz * Tsz;
        const int* mkb = mask + b * Ssz;
        const int s_lo = c * 32 + 1;
        const int s_hi = min(c * 32 + 32, Ssz - 1);

        float ec[Tsz];
#pragma unroll
        for (int j = 0; j < Tsz; ++j) ec[j] = emb[s_lo * Tsz + j];
        int mc = mkb[s_lo];

        for (int s = s_lo; s <= s_hi; ++s) {
            const int sp = (s < s_hi) ? s + 1 : s;
            float en[Tsz];
#pragma unroll
            for (int j = 0; j < Tsz; ++j) en[j] = emb[sp * Tsz + j];
            const int mn = mkb[sp];

            float g[Tsz];
#pragma unroll
            for (int j = 0; j < Tsz; ++j) g[j] = row[0] + T[j];
#pragma unroll
            for (int i = 1; i < Tsz; ++i)
#pragma unroll
                for (int j = 0; j < Tsz; ++j) g[j] = fmaxf(g[j], row[i] + T[i * Tsz + j]);
#pragma unroll
            for (int j = 0; j < Tsz; ++j)
                if (mc > 0) row[j] = g[j] + ec[j];
#pragma unroll
            for (int j = 0; j < Tsz; ++j) ec[j] = en[j];
            mc = mn;
        }
        float* o = MV + (size_t)bc * 81 + a * Tsz;
#pragma unroll
        for (int j = 0; j < Tsz; ++j) o[j] = row[j];
    }
}

// first-max argmax of 9 values (strict > keeps FIRST max)
__device__ __forceinline__ void amax9(const float (&v)[Tsz], float& bv, int& bi) {
    float w01v = (v[1] > v[0]) ? v[1] : v[0]; int w01i = (v[1] > v[0]) ? 1 : 0;
    float w23v = (v[3] > v[2]) ? v[3] : v[2]; int w23i = (v[3] > v[2]) ? 3 : 2;
    float w45v = (v[5] > v[4]) ? v[5] : v[4]; int w45i = (v[5] > v[4]) ? 5 : 4;
    float w67v = (v[7] > v[6]) ? v[7] : v[6]; int w67i = (v[7] > v[6]) ? 7 : 6;
    float x03v = (w23v > w01v) ? w23v : w01v; int x03i = (w23v > w01v) ? w23i : w01i;
    float x47v = (w67v > w45v) ? w67v : w45v; int x47i = (w67v > w45v) ? w67i : w45i;
    float y07v = (x47v > x03v) ? x47v : x03v; int y07i = (x47v > x03v) ? x47i : x03i;
    bv = (v[8] > y07v) ? v[8] : y07v;
    bi = (v[8] > y07v) ? 8 : y07i;
}

// ---------------- K3: per-batch finish (192 threads, no big reg arrays) ---------
__global__ __launch_bounds__(192, 1) void vit3_kernel(
    const float* __restrict__ em, const int* __restrict__ labels,
    const int* __restrict__ mask, const float* __restrict__ start_t,
    const float* __restrict__ end_t, const float* __restrict__ trans,
    const float* __restrict__ R2, const float* __restrict__ MV,
    float* __restrict__ out_path, float* __restrict__ ll) {
    __shared__ __align__(16) float em_s[4640];          // skewed [s][j]
    __shared__ __align__(16) int   mk_s[Ssz];
    __shared__ __align__(16) float mv_s[NCH * 81];
    __shared__ __align__(16) float r2_s[NCH * 81];
    __shared__ float tr_s[81];
    __shared__ float st_s[12], en_s[12];
    __shared__ __align__(16) float alc[2][NCH][12];     // viterbi chunk alphas
    __shared__ float a2c[2][12];                        // den alphas (log2)
    __shared__ unsigned char bp[(Ssz - 1) * Tsz];
    __shared__ unsigned char mapA[64][12], mapB[64][12];
    __shared__ float den_sh, num_sh;

    const int b = blockIdx.x, tid = threadIdx.x;
    const int wv = tid >> 6, ln = tid & 63;
    const int c = tid / 12, j9 = tid % 12;              // c < 16 always
    const float* emb = em + (size_t)b * Ssz * Tsz;
    const int* mkb = mask + b * Ssz;
    const int* lbb = labels + b * Ssz;

    // ---- phase 0: staging ----
    for (int i = tid; i < Ssz * Tsz; i += 192) {
        const int s = i / 9, j = i - s * 9;
        em_s[SK(s) + j] = emb[i];
    }
    for (int i = tid; i < Ssz; i += 192) mk_s[i] = mkb[i];
    {
        const float4* v4 = reinterpret_cast<const float4*>(MV + (size_t)b * NCH * 81);
        float4* vd = reinterpret_cast<float4*>(mv_s);
        for (int i = tid; i < NCH * 81 / 4; i += 192) vd[i] = v4[i];
        const float4* r4 = reinterpret_cast<const float4*>(R2 + (size_t)b * NCH * 81);
        float4* rd = reinterpret_cast<float4*>(r2_s);
        for (int i = tid; i < NCH * 81 / 4; i += 192) rd[i] = r4[i];
        if (tid < 81) tr_s[tid] = trans[tid];
        if (tid >= 96 && tid < 96 + Tsz) {
            st_s[tid - 96] = start_t[tid - 96];
            en_s[tid - 96] = end_t[tid - 96];
        }
    }
    __syncthreads();

    float tc[Tsz];                                       // transition column j9
    const int jj = (j9 < Tsz) ? j9 : Tsz - 1;
#pragma unroll
    for (int i = 0; i < Tsz; ++i) tc[i] = tr_s[i * Tsz + jj];

    float aj = 0.0f;
    if (c == 0 && j9 < Tsz) {
        aj = st_s[j9] + em_s[j9];
        alc[0][0][j9] = aj;
    }
    if (wv == 1 && ln < Tsz) a2c[0][ln] = (st_s[ln] + em_s[ln]) * LOG2E;

    // ---- phase A: 16 rounds — vit prefix chain + den combine chain ----
    for (int r = 0; r < NCH; ++r) {
        __syncthreads();
        if (r < NCH - 1 && c == r + 1 && j9 < Tsz) {
            const float* M = &mv_s[r * 81];
            float m = alc[0][r][0] + M[j9];
#pragma unroll
            for (int i = 1; i < Tsz; ++i)
                m = fmaxf(m, alc[0][r][i] + M[i * Tsz + j9]);
            aj = m;
            alc[0][c][j9] = m;
        }
        if (wv == 1 && ln < Tsz) {
            const float* Rr = &r2_s[r * 81];
            float xi[Tsz];
#pragma unroll
            for (int i = 0; i < Tsz; ++i) xi[i] = a2c[r & 1][i] + Rr[i * Tsz + ln];
            float m = xi[0];
#pragma unroll
            for (int i = 1; i < Tsz; ++i) m = fmaxf(m, xi[i]);
            float sm = 0.0f;
#pragma unroll
            for (int i = 0; i < Tsz; ++i) sm += exp2f(xi[i] - m);
            a2c[(r + 1) & 1][ln] = m + __log2f(sm);
        }
    }

    // ---- phase B: chunk-parallel viterbi scan, 32 barrier-steps ----
    int pb = 0;
    for (int k = 0; k < 32; ++k) {
        __syncthreads();
        const int s = c * 32 + 1 + k;
        if (j9 < Tsz && s <= Ssz - 1) {
            const int mk = mk_s[s];
            float av[12];
            const float4* ap = reinterpret_cast<const float4*>(&alc[pb][c][0]);
            *reinterpret_cast<float4*>(&av[0]) = ap[0];
            *reinterpret_cast<float4*>(&av[4]) = ap[1];
            *reinterpret_cast<float4*>(&av[8]) = ap[2];
            float v[Tsz];
#pragma unroll
            for (int i = 0; i < Tsz; ++i) v[i] = av[i] + tc[i];
            float bv; int bi;
            amax9(v, bv, bi);
            bp[(s - 1) * Tsz + j9] = (unsigned char)((mk > 0) ? bi : j9);
            if (mk > 0) aj = bv + em_s[SK(s) + j9];
        }
        if (j9 < Tsz) alc[1 - pb][c][j9] = aj;
        pb ^= 1;
    }
    __syncthreads();
    // final alphas now in alc[0][15][*]

    // ---- last tag (computed redundantly) ----
    float bb = alc[0][NCH - 1][0] + en_s[0];
    int last = 0;
#pragma unroll
    for (int q = 1; q < Tsz; ++q) {
        const float qq = alc[0][NCH - 1][q] + en_s[q];
        if (qq > bb) { bb = qq; last = q; }
    }

    // ---- section S1 (no barriers): wave0 chunk maps, wave1 den final, wave2 num --
    const int lo = ln * 8;
    const int hi = min(lo + 7, Ssz - 2);
    if (wv == 0) {
        int xf[Tsz];
#pragma unroll
        for (int t = 0; t < Tsz; ++t) xf[t] = t;
        for (int k = hi; k >= lo; --k) {
#pragma unroll
            for (int t = 0; t < Tsz; ++t) xf[t] = bp[k * Tsz + xf[t]];
        }
#pragma unroll
        for (int t = 0; t < Tsz; ++t) mapA[ln][t] = (unsigned char)xf[t];
    } else if (wv == 1) {
        if (ln == 0) {
            float xv[Tsz];
#pragma unroll
            for (int i = 0; i < Tsz; ++i) xv[i] = a2c[0][i] + en_s[i] * LOG2E;
            float m = xv[0];
#pragma unroll
            for (int i = 1; i < Tsz; ++i) m = fmaxf(m, xv[i]);
            float sm = 0.0f;
#pragma unroll
            for (int i = 0; i < Tsz; ++i) sm += exp2f(xv[i] - m);
            den_sh = m + __log2f(sm);
        }
    } else {
        float part = 0.0f;
        for (int s = 1 + ln; s < Ssz; s += 64) {
            if (mk_s[s] > 0) {
                const int tg = lbb[s];
                int pq = s - 1;
                while (pq > 0 && mk_s[pq] == 0) --pq;
                part += tr_s[lbb[pq] * Tsz + tg] + em_s[SK(s) + tg];
            }
        }
#pragma unroll
        for (int off = 32; off >= 1; off >>= 1) part += __shfl_xor(part, off, 64);
        if (ln == 0) {
            const int tg0 = lbb[0];
            float num = part + st_s[tg0] + em_s[tg0];
            int pq = Ssz - 1;
            while (pq > 0 && mk_s[pq] == 0) --pq;
            num += en_s[lbb[pq]];
            num_sh = num;
        }
    }

    // ---- suffix-composition doubling (all threads hit barriers) ----
#define VIT_RND(CUR, NXT, D)                                               \
    {                                                                      \
        unsigned char nn[Tsz];                                             \
        if (wv == 0) {                                                     \
            const int o = ln + (D);                                        \
            if (o < 64) {                                                  \
                _Pragma("unroll") for (int t = 0; t < Tsz; ++t)            \
                    nn[t] = CUR[ln][CUR[o][t]];                            \
            } else {                                                       \
                _Pragma("unroll") for (int t = 0; t < Tsz; ++t)            \
                    nn[t] = CUR[ln][t];                                    \
            }                                                              \
        }                                                                  \
        __syncthreads();                                                   \
        if (wv == 0) {                                                     \
            _Pragma("unroll") for (int t = 0; t < Tsz; ++t)                \
                NXT[ln][t] = nn[t];                                        \
        }                                                                  \
        __syncthreads();                                                   \
    }
    VIT_RND(mapA, mapB, 1)
    VIT_RND(mapB, mapA, 2)
    VIT_RND(mapA, mapB, 4)
    VIT_RND(mapB, mapA, 8)
    VIT_RND(mapA, mapB, 16)
    VIT_RND(mapB, mapA, 32)
#undef VIT_RND

    if (wv == 0) {
        int t = (ln == 63) ? last : (int)mapA[ln + 1][last];
        float* op = out_path + (size_t)b * Ssz;
        for (int k = hi; k >= lo; --k) {
            t = bp[k * Tsz + t];
            op[k] = (float)t;
        }
        if (ln == 0) op[Ssz - 1] = (float)last;
    }
    if (tid == 0) ll[b] = num_sh - den_sh * LN2F;
}

// ---------------- K4: loss reduce + lengths ----------------
__global__ __launch_bounds__(64) void fin2_kernel(const float* __restrict__ ll,
                                                  const int* __restrict__ lengths,
                                                  float* __restrict__ dout) {
    const int lane = threadIdx.x;
    float v = ll[lane];
#pragma unroll
    for (int off = 32; off >= 1; off >>= 1) v += __shfl_xor(v, off, 64);
    if (lane == 0) dout[0] = -v * (1.0f / (float)Bsz);
    dout[1 + Bsz * Ssz + lane] = (float)lengths[lane];
}

extern "C" void kernel_launch(void* const* d_in, const int* in_sizes, int n_in,
                              void* d_out, int out_size, void* d_ws, size_t ws_size,
                              hipStream_t stream) {
    const float* enc    = (const float*)d_in[0];
    const int*   labels = (const int*)d_in[1];
    const int*   mask   = (const int*)d_in[2];
    const int*   lengths= (const int*)d_in[3];
    const float* fcw    = (const float*)d_in[4];
    const float* fcb    = (const float*)d_in[5];
    const float* startt = (const float*)d_in[6];
    const float* endt   = (const float*)d_in[7];
    const float* trans  = (const float*)d_in[8];

    float* out = (float*)d_out;
    float* em  = (float*)d_ws;                                // 294912 f
    float* R2  = em + (size_t)Bsz * Ssz * Tsz;                // 82944 f
    float* MV  = R2 + (size_t)Bsz * NCH * 81;                 // 82944 f
    float* ll  = MV + (size_t)Bsz * NCH * 81;                 // 64 f

    emis_kernel<<<Bsz * Ssz / 16, 256, 0, stream>>>(enc, fcw, fcb, em);
    pass1_kernel<<<72, 256, 0, stream>>>(em, mask, trans, R2, MV);
    vit3_kernel<<<Bsz, 192, 0, stream>>>(em, labels, mask, startt, endt, trans,
                                         R2, MV, out + 1, ll);
    fin2_kernel<<<1, 64, 0, stream>>>(ll, lengths, out);
}